// Round 1
// baseline (507.812 us; speedup 1.0000x reference)
//
#include <hip/hip_runtime.h>

// ---------------------------------------------------------------------------
// SpatialSatCrossAttention (MS deformable attention, 6 cams, 10000 queries)
// R8: vproj stored f32 (kills the bf16-unpack VALU tax in sample_k, which was
//     82% VALUBusy / 0 Mfma); qkcat stored bf16; slots embedded into qkcat's
//     attw region (read-before-write within each block) to keep ws <= 53 MB.
//     pack8 (f32->bf16 staging in GEMMs) now uses v_cvt_pk_bf16_f32.
// Launches (4):
//   1. prep_w    : weight mats -> Wt[n][k] bf16 (512 blocks)
//   2. gemm_vqk  : vproj = value @ value_W + b  (f32 out)
//                  qkcat = query @ [off|attw]_W (bf16 out)
//   3. sample_k  : deformable bilinear sampling (f32 gather, pk_fma, no
//                  unpack) -> slots bf16 embedded in qkcat[:,512:768]
//   4. gemm_out  : out = slots @ out_W + out_b + query (f32 d_out)
// GEMM body: 128x128 tile, 4 waves (2x2), 4x4 mfma_f32_16x16x32_bf16, BK=32,
// double-buffered LDS + register prefetch.
// ---------------------------------------------------------------------------

typedef unsigned short ushort_t;
typedef unsigned int uint_t;
typedef __attribute__((ext_vector_type(8))) short bf16x8;
typedef __attribute__((ext_vector_type(4))) float f32x4;
typedef __attribute__((ext_vector_type(2))) float f32x2;

__device__ __forceinline__ float bf2f(ushort_t u) {
    return __uint_as_float(((uint_t)u) << 16);
}
__device__ __forceinline__ ushort_t f2bf(float f) {
    uint_t i = __float_as_uint(f);
    uint_t r = i + 0x7fffu + ((i >> 16) & 1u);   // round-to-nearest-even
    return (ushort_t)(r >> 16);
}
// 8x f32 -> 8x bf16 via v_cvt_pk_bf16_f32 (RNE, 4 insts instead of ~40)
__device__ __forceinline__ bf16x8 pack8(float4 v0, float4 v1) {
    union { uint_t u[4]; bf16x8 v; } r;
    asm("v_cvt_pk_bf16_f32 %0, %1, %2" : "=v"(r.u[0]) : "v"(v0.x), "v"(v0.y));
    asm("v_cvt_pk_bf16_f32 %0, %1, %2" : "=v"(r.u[1]) : "v"(v0.z), "v"(v0.w));
    asm("v_cvt_pk_bf16_f32 %0, %1, %2" : "=v"(r.u[2]) : "v"(v1.x), "v"(v1.y));
    asm("v_cvt_pk_bf16_f32 %0, %1, %2" : "=v"(r.u[3]) : "v"(v1.z), "v"(v1.w));
    return r.v;
}

// ---------------------------------------------------------------------------
// prep_w: weight transpose+convert only. W[k][N] f32 -> T[n][256] bf16.
// grid (8,16,4): z=0 value_W, z=1 out_W, z=2 off_W(512), z=3 attw_W.
// ---------------------------------------------------------------------------
__global__ __launch_bounds__(256) void prep_w(
    const float* __restrict__ Wv, const float* __restrict__ Wo,
    const float* __restrict__ Wf, const float* __restrict__ Wa,
    ushort_t* __restrict__ Tv, ushort_t* __restrict__ To,
    ushort_t* __restrict__ Tqk) {
    const int z = blockIdx.z;
    const float* W;
    ushort_t* T;
    int N;
    if (z == 0)      { W = Wv; T = Tv;              N = 256; }
    else if (z == 1) { W = Wo; T = To;              N = 256; }
    else if (z == 2) { W = Wf; T = Tqk;             N = 512; }
    else             { W = Wa; T = Tqk + 512 * 256; N = 256; }
    const int n0 = blockIdx.y * 32;
    if (n0 >= N) return;
    const int k0 = blockIdx.x * 32;

    __shared__ float tile[32][33];
    const int tx = threadIdx.x & 31;
    const int ty = threadIdx.x >> 5;   // 0..7
    #pragma unroll
    for (int r = 0; r < 4; ++r) {
        const int k = ty + r * 8;
        tile[k][tx] = W[(size_t)(k0 + k) * N + n0 + tx];
    }
    __syncthreads();
    #pragma unroll
    for (int r = 0; r < 4; ++r) {
        const int n = ty + r * 8;
        T[(size_t)(n0 + n) * 256 + k0 + tx] = f2bf(tile[tx][n]);
    }
}

// ---------------------------------------------------------------------------
// MFMA GEMM body: C[M,N] = A[M,256] @ Wt^T + bias (+resid).
// AF32: A is f32, converted to bf16 during LDS staging; else A is bf16.
// Astride: element stride between A rows (supports slots embedded in qkcat).
// Wt bf16 [N][256]. N multiple of 128. 256 threads, 128x128 tile.
// ---------------------------------------------------------------------------
template <bool AF32, bool OUT_BF16, bool RESID>
__device__ __forceinline__ void gemm_body(
    ushort_t (*sA)[128][32], ushort_t (*sB)[128][32],
    const void* __restrict__ Av, int Astride, const ushort_t* __restrict__ Wt,
    const float* __restrict__ bias0, const float* __restrict__ bias1, int split,
    const float* __restrict__ resid, void* __restrict__ Cv,
    int M, int N, int bx, int by) {
    const int m0 = bx * 128;
    const int n0 = by * 128;
    const int t    = threadIdx.x;
    const int lane = t & 63;
    const int w    = t >> 6;
    const int wr   = w >> 1, wc = w & 1;

    const int srow = t >> 2;          // 0..63
    const int skof = (t & 3) * 8;     // 0,8,16,24

    const bool am0 = (m0 + srow) < M;
    const bool am1 = (m0 + 64 + srow) < M;
    const float*    Af0 = (const float*)Av + (size_t)(m0 + srow) * Astride + skof;
    const float*    Af1 = Af0 + (size_t)64 * Astride;
    const ushort_t* Ab0 = (const ushort_t*)Av + (size_t)(m0 + srow) * Astride + skof;
    const ushort_t* Ab1 = Ab0 + (size_t)64 * Astride;
    const ushort_t* Bp0 = Wt + (size_t)(n0 + srow) * 256 + skof;
    const ushort_t* Bp1 = Bp0 + (size_t)64 * 256;

    const bf16x8 zz = {0, 0, 0, 0, 0, 0, 0, 0};

    auto loadA = [&](const float* af, const ushort_t* ab, int ko, bool ok) -> bf16x8 {
        if (!ok) return zz;
        if (AF32) {
            const float4 v0 = *(const float4*)(af + ko);
            const float4 v1 = *(const float4*)(af + ko + 4);
            return pack8(v0, v1);
        }
        return *(const bf16x8*)(ab + ko);
    };

    f32x4 acc[4][4];
    #pragma unroll
    for (int i = 0; i < 4; ++i)
        #pragma unroll
        for (int j = 0; j < 4; ++j)
            acc[i][j] = (f32x4){0.f, 0.f, 0.f, 0.f};

    // prologue: tile 0 -> LDS[0]
    {
        const bf16x8 a0 = loadA(Af0, Ab0, 0, am0);
        const bf16x8 a1 = loadA(Af1, Ab1, 0, am1);
        const bf16x8 b0 = *(const bf16x8*)(Bp0);
        const bf16x8 b1 = *(const bf16x8*)(Bp1);
        *(bf16x8*)(&sA[0][srow][skof])      = a0;
        *(bf16x8*)(&sA[0][64 + srow][skof]) = a1;
        *(bf16x8*)(&sB[0][srow][skof])      = b0;
        *(bf16x8*)(&sB[0][64 + srow][skof]) = b1;
    }
    __syncthreads();

    const int rl = lane & 15;
    const int kq = (lane >> 4) * 8;

    for (int k = 0; k < 8; ++k) {
        const int buf = k & 1;

        bf16x8 na0 = zz, na1 = zz, nb0 = zz, nb1 = zz;
        if (k < 7) {
            const int ko = (k + 1) * 32;
            na0 = loadA(Af0, Ab0, ko, am0);
            na1 = loadA(Af1, Ab1, ko, am1);
            nb0 = *(const bf16x8*)(Bp0 + ko);
            nb1 = *(const bf16x8*)(Bp1 + ko);
        }

        bf16x8 af[4], bfr[4];
        #pragma unroll
        for (int i = 0; i < 4; ++i)
            af[i] = *(const bf16x8*)(&sA[buf][wr * 64 + i * 16 + rl][kq]);
        #pragma unroll
        for (int j = 0; j < 4; ++j)
            bfr[j] = *(const bf16x8*)(&sB[buf][wc * 64 + j * 16 + rl][kq]);
        #pragma unroll
        for (int i = 0; i < 4; ++i)
            #pragma unroll
            for (int j = 0; j < 4; ++j)
                acc[i][j] = __builtin_amdgcn_mfma_f32_16x16x32_bf16(
                    af[i], bfr[j], acc[i][j], 0, 0, 0);

        if (k < 7) {
            __syncthreads();
            *(bf16x8*)(&sA[buf ^ 1][srow][skof])      = na0;
            *(bf16x8*)(&sA[buf ^ 1][64 + srow][skof]) = na1;
            *(bf16x8*)(&sB[buf ^ 1][srow][skof])      = nb0;
            *(bf16x8*)(&sB[buf ^ 1][64 + srow][skof]) = nb1;
            __syncthreads();
        }
    }

    // --- epilogue: C/D layout col=lane&15, row=(lane>>4)*4+reg (m89) ---
    const int col_l = lane & 15;
    const int rq    = (lane >> 4) * 4;
    #pragma unroll
    for (int j = 0; j < 4; ++j) {
        const int gn = n0 + wc * 64 + j * 16 + col_l;
        const float bj = (gn < split) ? bias0[gn] : bias1[gn - split];
        #pragma unroll
        for (int i = 0; i < 4; ++i) {
            #pragma unroll
            for (int r = 0; r < 4; ++r) {
                const int gm = m0 + wr * 64 + i * 16 + rq + r;
                if (gm >= M) continue;
                float v = acc[i][j][r] + bj;
                if (RESID) v += resid[(size_t)gm * N + gn];
                if (OUT_BF16)
                    ((ushort_t*)Cv)[(size_t)gm * N + gn] = f2bf(v);
                else
                    ((float*)Cv)[(size_t)gm * N + gn] = v;
            }
        }
    }
}

// Fused independent GEMMs: blocks [0,510) -> vproj (f32 out),
//                          [510,984) -> qkcat (bf16 out).
__global__ __launch_bounds__(256) void gemm_vqk(
    const float* __restrict__ value, const ushort_t* __restrict__ value_Wt,
    const float* __restrict__ value_b, float* __restrict__ vproj,
    const float* __restrict__ query, const ushort_t* __restrict__ qk_Wt,
    const float* __restrict__ off_b, const float* __restrict__ attw_b,
    ushort_t* __restrict__ qkcat) {
    __shared__ ushort_t sA[2][128][32];
    __shared__ ushort_t sB[2][128][32];
    int b = blockIdx.x;
    if (b < 510) {
        gemm_body<true, false, false>(sA, sB, value, 256, value_Wt, value_b,
                                      value_b, 256, nullptr, (void*)vproj,
                                      32640, 256, b % 255, b / 255);
    } else {
        b -= 510;
        gemm_body<true, true, false>(sA, sB, query, 256, qk_Wt, off_b, attw_b,
                                     512, nullptr, (void*)qkcat, 10000, 768,
                                     b % 79, b / 79);
    }
}

__global__ __launch_bounds__(256) void gemm_out_k(
    const ushort_t* __restrict__ slots,   // = qkcat + 512, row stride 768
    const ushort_t* __restrict__ out_Wt,
    const float* __restrict__ out_b, const float* __restrict__ query,
    float* __restrict__ out) {
    __shared__ ushort_t sA[2][128][32];
    __shared__ ushort_t sB[2][128][32];
    gemm_body<false, false, true>(sA, sB, slots, 768, out_Wt, out_b, out_b, 256,
                                  query, (void*)out, 10000, 256,
                                  blockIdx.x, blockIdx.y);
}

// ---------------------------------------------------------------------------
// Deformable sampling. 1 block per query, 256 threads.
//   setup role : (h, lp = tid&31)  -> corner idx/weights for its (h,lvl,p)
//   gather role: (h, slice, g)     -> f32 dwordx4 pairs (8 ch), no unpack
// Corner (idx,w) exchanged via __shfl within the wave. f32x2 accumulators
// (v_pk_fma_f32). Slot row written back into qkcat[:,512:768) as bf16
// (every thread reads its attw logit before any thread writes).
// ---------------------------------------------------------------------------
__global__ __launch_bounds__(256) void sample_k(
    ushort_t* __restrict__ qkcat,       // bf16 [10000, 768]
    const float* __restrict__ refp,     // f32 [6,1,10000,4,2]
    const int* __restrict__ vox,        // int32 [6,1,10000,4]
    const float* __restrict__ vproj) {  // f32 [6*5440, 256]
    const int q   = blockIdx.x;
    const int tid = threadIdx.x;
    const int lane  = tid & 63;
    const int h     = tid >> 5;
    const int lp    = tid & 31;          // setup role
    const int slice = (tid >> 2) & 7;    // gather role
    const int g     = tid & 3;           // gather role: channels g*8..g*8+7

    __shared__ float s_valid[8];
    __shared__ float s_red[256][8];      // [tid][chan-in-group]

    if (tid < 6) {
        const int base = (tid * 10000 + q) * 4;
        const int mm = vox[base] | vox[base + 1] | vox[base + 2] | vox[base + 3];
        s_valid[tid] = mm ? 1.0f : 0.0f;
    }

    // ---- softmax over 32 (lvl,p) entries within each head ----
    const float a = bf2f(qkcat[(size_t)q * 768 + 512 + tid]);
    float mx = a;
    #pragma unroll
    for (int o = 16; o >= 1; o >>= 1) mx = fmaxf(mx, __shfl_xor(mx, o));
    const float e = __expf(a - mx);
    float se = e;
    #pragma unroll
    for (int o = 16; o >= 1; o >>= 1) se += __shfl_xor(se, o);
    const float aw = e / se;

    // ---- camera-independent part of this thread's sample location ----
    const int lvl = lp >> 3;
    const int p   = lp & 7;
    const int dd  = p & 3;
    const int   Sarr[4]   = {64, 32, 16, 8};
    const int   Lstart[4] = {0, 4096, 5120, 5376};
    const int   S  = Sarr[lvl];
    const float Sf = (float)S;
    const int   lstart = Lstart[lvl];
    const float ox = bf2f(qkcat[(size_t)q * 768 + h * 64 + lvl * 16 + p * 2 + 0]) / Sf;
    const float oy = bf2f(qkcat[(size_t)q * 768 + h * 64 + lvl * 16 + p * 2 + 1]) / Sf;

    __syncthreads();
    const float cnt = s_valid[0] + s_valid[1] + s_valid[2] +
                      s_valid[3] + s_valid[4] + s_valid[5];

    f32x2 acc2[4] = {{0.f, 0.f}, {0.f, 0.f}, {0.f, 0.f}, {0.f, 0.f}};
    const float* vp = vproj + (g << 3);
    const int srcbase = (lane & 32) + slice * 4;

    for (int c = 0; c < 6; ++c) {
        if (s_valid[c] == 0.0f) continue;   // block-uniform branch

        // ---- setup: this (h,lvl,p) sample's 4 corner indices + weights ----
        int   ci0, ci1, ci2, ci3;
        float cw0, cw1, cw2, cw3;
        {
            const int rbase = ((c * 10000 + q) * 4 + dd) * 2;
            const float rx = refp[rbase + 0];
            const float ry = refp[rbase + 1];
            const float x  = (rx + ox) * Sf - 0.5f;
            const float y  = (ry + oy) * Sf - 0.5f;
            const float x0 = floorf(x), y0 = floorf(y);
            int   ci[4];
            float cw[4];
            #pragma unroll
            for (int k = 0; k < 4; ++k) {
                const float cx = x0 + (float)(k & 1);
                const float cy = y0 + (float)(k >> 1);
                const float wgt = (1.0f - fabsf(x - cx)) * (1.0f - fabsf(y - cy));
                const bool ok = (cx >= 0.0f) & (cx < Sf) & (cy >= 0.0f) & (cy < Sf);
                const int xi = (int)fminf(fmaxf(cx, 0.0f), Sf - 1.0f);
                const int yi = (int)fminf(fmaxf(cy, 0.0f), Sf - 1.0f);
                ci[k] = (c * 5440 + lstart + yi * S + xi) * 256 + h * 32;
                cw[k] = ok ? wgt * aw : 0.0f;
            }
            ci0 = ci[0]; ci1 = ci[1]; ci2 = ci[2]; ci3 = ci[3];
            cw0 = cw[0]; cw1 = cw[1]; cw2 = cw[2]; cw3 = cw[3];
        }

        // ---- gather: 4 lp x 4 corners; idx/w via in-wave shuffle ----
        #pragma unroll
        for (int j = 0; j < 4; ++j) {
            const int src = srcbase + j;
            const int i0 = __shfl(ci0, src), i1 = __shfl(ci1, src);
            const int i2 = __shfl(ci2, src), i3 = __shfl(ci3, src);
            const float w0 = __shfl(cw0, src), w1 = __shfl(cw1, src);
            const float w2 = __shfl(cw2, src), w3 = __shfl(cw3, src);
            const f32x4 a0 = *(const f32x4*)(vp + i0);
            const f32x4 b0 = *(const f32x4*)(vp + i0 + 4);
            const f32x4 a1 = *(const f32x4*)(vp + i1);
            const f32x4 b1 = *(const f32x4*)(vp + i1 + 4);
            const f32x4 a2 = *(const f32x4*)(vp + i2);
            const f32x4 b2 = *(const f32x4*)(vp + i2 + 4);
            const f32x4 a3 = *(const f32x4*)(vp + i3);
            const f32x4 b3 = *(const f32x4*)(vp + i3 + 4);
            const f32x2 W0 = {w0, w0}, W1 = {w1, w1}, W2 = {w2, w2}, W3 = {w3, w3};
            acc2[0] += W0 * (f32x2){a0[0], a0[1]};
            acc2[1] += W0 * (f32x2){a0[2], a0[3]};
            acc2[2] += W0 * (f32x2){b0[0], b0[1]};
            acc2[3] += W0 * (f32x2){b0[2], b0[3]};
            acc2[0] += W1 * (f32x2){a1[0], a1[1]};
            acc2[1] += W1 * (f32x2){a1[2], a1[3]};
            acc2[2] += W1 * (f32x2){b1[0], b1[1]};
            acc2[3] += W1 * (f32x2){b1[2], b1[3]};
            acc2[0] += W2 * (f32x2){a2[0], a2[1]};
            acc2[1] += W2 * (f32x2){a2[2], a2[3]};
            acc2[2] += W2 * (f32x2){b2[0], b2[1]};
            acc2[3] += W2 * (f32x2){b2[2], b2[3]};
            acc2[0] += W3 * (f32x2){a3[0], a3[1]};
            acc2[1] += W3 * (f32x2){a3[2], a3[3]};
            acc2[2] += W3 * (f32x2){b3[0], b3[1]};
            acc2[3] += W3 * (f32x2){b3[2], b3[3]};
        }
    }

    // ---- cross-slice reduction ----
    #pragma unroll
    for (int n = 0; n < 4; ++n) {
        s_red[tid][2 * n]     = acc2[n].x;
        s_red[tid][2 * n + 1] = acc2[n].y;
    }
    __syncthreads();

    const int cch = tid & 31;
    float sum = 0.0f;
    #pragma unroll
    for (int s = 0; s < 8; ++s)
        sum += s_red[h * 32 + s * 4 + (cch >> 3)][cch & 7];

    // slot row overwrites this query's attw logits (all read above)
    qkcat[(size_t)q * 768 + 512 + tid] = f2bf(sum / fmaxf(cnt, 1.0f));
}

// ---------------------------------------------------------------------------
extern "C" void kernel_launch(void* const* d_in, const int* in_sizes, int n_in,
                              void* d_out, int out_size, void* d_ws, size_t ws_size,
                              hipStream_t stream) {
    const float* query   = (const float*)d_in[0];
    // d_in[1] = key : unused by the deformable-attention math
    const float* value   = (const float*)d_in[2];   // (6,5440,1,256) -> (32640,256)
    const float* refp    = (const float*)d_in[3];
    const int*   vox     = (const int*)d_in[4];
    // d_in[5] spatial_shapes, d_in[6] level_start_index : compile-time constants
    const float* value_W = (const float*)d_in[7];
    const float* value_b = (const float*)d_in[8];
    const float* off_W   = (const float*)d_in[9];
    const float* off_b   = (const float*)d_in[10];
    const float* attw_W  = (const float*)d_in[11];
    const float* attw_b  = (const float*)d_in[12];
    const float* out_W   = (const float*)d_in[13];
    const float* out_b   = (const float*)d_in[14];
    float* out = (float*)d_out;

    // ws layout (bytes):
    //   [0,        33423360)  vproj f32 [32640][256]
    //   [33423360, 48783360)  qkcat bf16 [10000][768] (slots live in cols 512..768)
    //   [48783360, 49438720)  value_Wt | out_Wt | qk_Wt  bf16
    char* ws = (char*)d_ws;
    float*    vproj    = (float*)ws;
    ushort_t* qkcat    = (ushort_t*)(ws + 33423360);
    ushort_t* value_Wt = (ushort_t*)(ws + 48783360);
    ushort_t* out_Wt   = (ushort_t*)(ws + 48783360 + 131072);
    ushort_t* qk_Wt    = (ushort_t*)(ws + 48783360 + 262144);

    // 1. weight transpose+convert -> Wt[n][k] bf16
    prep_w<<<dim3(8, 16, 4), 256, 0, stream>>>(
        value_W, out_W, off_W, attw_W, value_Wt, out_Wt, qk_Wt);
    // 2. fused value-proj (f32 out) + offset/attw-proj (bf16 out)
    gemm_vqk<<<984, 256, 0, stream>>>(value, value_Wt, value_b, vproj,
                                      query, qk_Wt, off_b, attw_b, qkcat);
    // 3. deformable sampling + softmax + camera mask/count -> slots in qkcat
    sample_k<<<10000, 256, 0, stream>>>(qkcat, refp, vox, vproj);
    // 4. output projection + residual, f32 out
    gemm_out_k<<<dim3(79, 2), 256, 0, stream>>>(qkcat + 512, out_Wt, out_b,
                                                query, out);
}

// Round 2
// 383.572 us; speedup vs baseline: 1.3239x; 1.3239x over previous
//
#include <hip/hip_runtime.h>

// ---------------------------------------------------------------------------
// SpatialSatCrossAttention (MS deformable attention, 6 cams, 10000 queries)
// R9: sample_k is L2-gather-BW/request-rate bound (~23 TB/s effective; R7 bf16
//     3.69GB/157us == R8 f32 7.4GB/328us). So: back to 2-byte gathers, but as
//     f16 + v_fma_mix_f32 (no unpack VALU, f32 accum), and deep prefetch:
//     all 16 gather loads of a camera in flight (byte offsets, SGPR base)
//     to lift TA/L2 utilization toward the ~94us request floor.
// Launches (4):
//   1. prep_w    : weight mats -> Wt[n][k] bf16 (512 blocks)
//   2. gemm_vqk  : vproj = value @ value_W + b  (f16 out)
//                  qkcat = query @ [off|attw]_W (bf16 out)
//   3. sample_k  : deformable bilinear sampling (f16 gather, fma_mix)
//                  -> slots bf16 embedded in qkcat[:,512:768]
//   4. gemm_out  : out = slots @ out_W + out_b + query (f32 d_out)
// GEMM body: 128x128 tile, 4 waves (2x2), 4x4 mfma_f32_16x16x32_bf16, BK=32,
// double-buffered LDS + register prefetch.
// ---------------------------------------------------------------------------

typedef unsigned short ushort_t;
typedef unsigned int uint_t;
typedef __attribute__((ext_vector_type(8))) short bf16x8;
typedef __attribute__((ext_vector_type(4))) float f32x4;

__device__ __forceinline__ float bf2f(ushort_t u) {
    return __uint_as_float(((uint_t)u) << 16);
}
__device__ __forceinline__ ushort_t f2bf(float f) {
    uint_t i = __float_as_uint(f);
    uint_t r = i + 0x7fffu + ((i >> 16) & 1u);   // round-to-nearest-even
    return (ushort_t)(r >> 16);
}
// 8x f32 -> 8x bf16 via v_cvt_pk_bf16_f32 (RNE)
__device__ __forceinline__ bf16x8 pack8(float4 v0, float4 v1) {
    union { uint_t u[4]; bf16x8 v; } r;
    asm("v_cvt_pk_bf16_f32 %0, %1, %2" : "=v"(r.u[0]) : "v"(v0.x), "v"(v0.y));
    asm("v_cvt_pk_bf16_f32 %0, %1, %2" : "=v"(r.u[1]) : "v"(v0.z), "v"(v0.w));
    asm("v_cvt_pk_bf16_f32 %0, %1, %2" : "=v"(r.u[2]) : "v"(v1.x), "v"(v1.y));
    asm("v_cvt_pk_bf16_f32 %0, %1, %2" : "=v"(r.u[3]) : "v"(v1.z), "v"(v1.w));
    return r.v;
}
__device__ __forceinline__ ushort_t f2h(float f) {
    union { _Float16 h; ushort_t u; } cv;
    cv.h = (_Float16)f;
    return cv.u;
}

// acc[0..7] += w * f16x8(v)   -- v_fma_mix_f32, f16 taken from dword halves
__device__ __forceinline__ void fma_mix8(float* a, float wt, const uint4& v) {
    asm("v_fma_mix_f32 %0, %1, %2, %0 op_sel_hi:[0,1,0]"
        : "+v"(a[0]) : "v"(wt), "v"(v.x));
    asm("v_fma_mix_f32 %0, %1, %2, %0 op_sel:[0,1,0] op_sel_hi:[0,1,0]"
        : "+v"(a[1]) : "v"(wt), "v"(v.x));
    asm("v_fma_mix_f32 %0, %1, %2, %0 op_sel_hi:[0,1,0]"
        : "+v"(a[2]) : "v"(wt), "v"(v.y));
    asm("v_fma_mix_f32 %0, %1, %2, %0 op_sel:[0,1,0] op_sel_hi:[0,1,0]"
        : "+v"(a[3]) : "v"(wt), "v"(v.y));
    asm("v_fma_mix_f32 %0, %1, %2, %0 op_sel_hi:[0,1,0]"
        : "+v"(a[4]) : "v"(wt), "v"(v.z));
    asm("v_fma_mix_f32 %0, %1, %2, %0 op_sel:[0,1,0] op_sel_hi:[0,1,0]"
        : "+v"(a[5]) : "v"(wt), "v"(v.z));
    asm("v_fma_mix_f32 %0, %1, %2, %0 op_sel_hi:[0,1,0]"
        : "+v"(a[6]) : "v"(wt), "v"(v.w));
    asm("v_fma_mix_f32 %0, %1, %2, %0 op_sel:[0,1,0] op_sel_hi:[0,1,0]"
        : "+v"(a[7]) : "v"(wt), "v"(v.w));
}

// ---------------------------------------------------------------------------
// prep_w: weight transpose+convert only. W[k][N] f32 -> T[n][256] bf16.
// grid (8,16,4): z=0 value_W, z=1 out_W, z=2 off_W(512), z=3 attw_W.
// ---------------------------------------------------------------------------
__global__ __launch_bounds__(256) void prep_w(
    const float* __restrict__ Wv, const float* __restrict__ Wo,
    const float* __restrict__ Wf, const float* __restrict__ Wa,
    ushort_t* __restrict__ Tv, ushort_t* __restrict__ To,
    ushort_t* __restrict__ Tqk) {
    const int z = blockIdx.z;
    const float* W;
    ushort_t* T;
    int N;
    if (z == 0)      { W = Wv; T = Tv;              N = 256; }
    else if (z == 1) { W = Wo; T = To;              N = 256; }
    else if (z == 2) { W = Wf; T = Tqk;             N = 512; }
    else             { W = Wa; T = Tqk + 512 * 256; N = 256; }
    const int n0 = blockIdx.y * 32;
    if (n0 >= N) return;
    const int k0 = blockIdx.x * 32;

    __shared__ float tile[32][33];
    const int tx = threadIdx.x & 31;
    const int ty = threadIdx.x >> 5;   // 0..7
    #pragma unroll
    for (int r = 0; r < 4; ++r) {
        const int k = ty + r * 8;
        tile[k][tx] = W[(size_t)(k0 + k) * N + n0 + tx];
    }
    __syncthreads();
    #pragma unroll
    for (int r = 0; r < 4; ++r) {
        const int n = ty + r * 8;
        T[(size_t)(n0 + n) * 256 + k0 + tx] = f2bf(tile[tx][n]);
    }
}

// ---------------------------------------------------------------------------
// MFMA GEMM body: C[M,N] = A[M,256] @ Wt^T + bias (+resid).
// AF32: A is f32, converted to bf16 during LDS staging; else A is bf16.
// OUT_MODE: 0 = f32, 1 = bf16, 2 = f16.
// Astride: element stride between A rows (slots live embedded in qkcat).
// Wt bf16 [N][256]. N multiple of 128. 256 threads, 128x128 tile.
// ---------------------------------------------------------------------------
template <bool AF32, int OUT_MODE, bool RESID>
__device__ __forceinline__ void gemm_body(
    ushort_t (*sA)[128][32], ushort_t (*sB)[128][32],
    const void* __restrict__ Av, int Astride, const ushort_t* __restrict__ Wt,
    const float* __restrict__ bias0, const float* __restrict__ bias1, int split,
    const float* __restrict__ resid, void* __restrict__ Cv,
    int M, int N, int bx, int by) {
    const int m0 = bx * 128;
    const int n0 = by * 128;
    const int t    = threadIdx.x;
    const int lane = t & 63;
    const int w    = t >> 6;
    const int wr   = w >> 1, wc = w & 1;

    const int srow = t >> 2;          // 0..63
    const int skof = (t & 3) * 8;     // 0,8,16,24

    const bool am0 = (m0 + srow) < M;
    const bool am1 = (m0 + 64 + srow) < M;
    const float*    Af0 = (const float*)Av + (size_t)(m0 + srow) * Astride + skof;
    const float*    Af1 = Af0 + (size_t)64 * Astride;
    const ushort_t* Ab0 = (const ushort_t*)Av + (size_t)(m0 + srow) * Astride + skof;
    const ushort_t* Ab1 = Ab0 + (size_t)64 * Astride;
    const ushort_t* Bp0 = Wt + (size_t)(n0 + srow) * 256 + skof;
    const ushort_t* Bp1 = Bp0 + (size_t)64 * 256;

    const bf16x8 zz = {0, 0, 0, 0, 0, 0, 0, 0};

    auto loadA = [&](const float* af, const ushort_t* ab, int ko, bool ok) -> bf16x8 {
        if (!ok) return zz;
        if (AF32) {
            const float4 v0 = *(const float4*)(af + ko);
            const float4 v1 = *(const float4*)(af + ko + 4);
            return pack8(v0, v1);
        }
        return *(const bf16x8*)(ab + ko);
    };

    f32x4 acc[4][4];
    #pragma unroll
    for (int i = 0; i < 4; ++i)
        #pragma unroll
        for (int j = 0; j < 4; ++j)
            acc[i][j] = (f32x4){0.f, 0.f, 0.f, 0.f};

    // prologue: tile 0 -> LDS[0]
    {
        const bf16x8 a0 = loadA(Af0, Ab0, 0, am0);
        const bf16x8 a1 = loadA(Af1, Ab1, 0, am1);
        const bf16x8 b0 = *(const bf16x8*)(Bp0);
        const bf16x8 b1 = *(const bf16x8*)(Bp1);
        *(bf16x8*)(&sA[0][srow][skof])      = a0;
        *(bf16x8*)(&sA[0][64 + srow][skof]) = a1;
        *(bf16x8*)(&sB[0][srow][skof])      = b0;
        *(bf16x8*)(&sB[0][64 + srow][skof]) = b1;
    }
    __syncthreads();

    const int rl = lane & 15;
    const int kq = (lane >> 4) * 8;

    for (int k = 0; k < 8; ++k) {
        const int buf = k & 1;

        bf16x8 na0 = zz, na1 = zz, nb0 = zz, nb1 = zz;
        if (k < 7) {
            const int ko = (k + 1) * 32;
            na0 = loadA(Af0, Ab0, ko, am0);
            na1 = loadA(Af1, Ab1, ko, am1);
            nb0 = *(const bf16x8*)(Bp0 + ko);
            nb1 = *(const bf16x8*)(Bp1 + ko);
        }

        bf16x8 af[4], bfr[4];
        #pragma unroll
        for (int i = 0; i < 4; ++i)
            af[i] = *(const bf16x8*)(&sA[buf][wr * 64 + i * 16 + rl][kq]);
        #pragma unroll
        for (int j = 0; j < 4; ++j)
            bfr[j] = *(const bf16x8*)(&sB[buf][wc * 64 + j * 16 + rl][kq]);
        #pragma unroll
        for (int i = 0; i < 4; ++i)
            #pragma unroll
            for (int j = 0; j < 4; ++j)
                acc[i][j] = __builtin_amdgcn_mfma_f32_16x16x32_bf16(
                    af[i], bfr[j], acc[i][j], 0, 0, 0);

        if (k < 7) {
            __syncthreads();
            *(bf16x8*)(&sA[buf ^ 1][srow][skof])      = na0;
            *(bf16x8*)(&sA[buf ^ 1][64 + srow][skof]) = na1;
            *(bf16x8*)(&sB[buf ^ 1][srow][skof])      = nb0;
            *(bf16x8*)(&sB[buf ^ 1][64 + srow][skof]) = nb1;
            __syncthreads();
        }
    }

    // --- epilogue: C/D layout col=lane&15, row=(lane>>4)*4+reg (m89) ---
    const int col_l = lane & 15;
    const int rq    = (lane >> 4) * 4;
    #pragma unroll
    for (int j = 0; j < 4; ++j) {
        const int gn = n0 + wc * 64 + j * 16 + col_l;
        const float bj = (gn < split) ? bias0[gn] : bias1[gn - split];
        #pragma unroll
        for (int i = 0; i < 4; ++i) {
            #pragma unroll
            for (int r = 0; r < 4; ++r) {
                const int gm = m0 + wr * 64 + i * 16 + rq + r;
                if (gm >= M) continue;
                float v = acc[i][j][r] + bj;
                if (RESID) v += resid[(size_t)gm * N + gn];
                if (OUT_MODE == 1)
                    ((ushort_t*)Cv)[(size_t)gm * N + gn] = f2bf(v);
                else if (OUT_MODE == 2)
                    ((ushort_t*)Cv)[(size_t)gm * N + gn] = f2h(v);
                else
                    ((float*)Cv)[(size_t)gm * N + gn] = v;
            }
        }
    }
}

// Fused independent GEMMs: blocks [0,510) -> vproj (f16 out),
//                          [510,984) -> qkcat (bf16 out).
__global__ __launch_bounds__(256) void gemm_vqk(
    const float* __restrict__ value, const ushort_t* __restrict__ value_Wt,
    const float* __restrict__ value_b, ushort_t* __restrict__ vproj,
    const float* __restrict__ query, const ushort_t* __restrict__ qk_Wt,
    const float* __restrict__ off_b, const float* __restrict__ attw_b,
    ushort_t* __restrict__ qkcat) {
    __shared__ ushort_t sA[2][128][32];
    __shared__ ushort_t sB[2][128][32];
    int b = blockIdx.x;
    if (b < 510) {
        gemm_body<true, 2, false>(sA, sB, value, 256, value_Wt, value_b,
                                  value_b, 256, nullptr, (void*)vproj,
                                  32640, 256, b % 255, b / 255);
    } else {
        b -= 510;
        gemm_body<true, 1, false>(sA, sB, query, 256, qk_Wt, off_b, attw_b,
                                  512, nullptr, (void*)qkcat, 10000, 768,
                                  b % 79, b / 79);
    }
}

__global__ __launch_bounds__(256) void gemm_out_k(
    const ushort_t* __restrict__ slots,   // = qkcat + 512, row stride 768
    const ushort_t* __restrict__ out_Wt,
    const float* __restrict__ out_b, const float* __restrict__ query,
    float* __restrict__ out) {
    __shared__ ushort_t sA[2][128][32];
    __shared__ ushort_t sB[2][128][32];
    gemm_body<false, 0, true>(sA, sB, slots, 768, out_Wt, out_b, out_b, 256,
                              query, (void*)out, 10000, 256,
                              blockIdx.x, blockIdx.y);
}

// ---------------------------------------------------------------------------
// Deformable sampling. 1 block per query, 256 threads.
//   setup role : (h, lp = tid&31)  -> corner byte-offset/weight for (h,lvl,p)
//   gather role: (h, slice, g)     -> 16B f16 loads, v_fma_mix accumulate
// All 16 gather loads of a camera issued before consumption (latency hiding);
// corner (idx,w) exchanged via __shfl. Slot row written back into
// qkcat[:,512:768) as bf16 (every thread reads its attw logit first).
// ---------------------------------------------------------------------------
__global__ __launch_bounds__(256) void sample_k(
    ushort_t* __restrict__ qkcat,        // bf16 [10000, 768]
    const float* __restrict__ refp,      // f32 [6,1,10000,4,2]
    const int* __restrict__ vox,         // int32 [6,1,10000,4]
    const ushort_t* __restrict__ vproj) {// f16 [6*5440, 256]
    const int q   = blockIdx.x;
    const int tid = threadIdx.x;
    const int lane  = tid & 63;
    const int h     = tid >> 5;
    const int lp    = tid & 31;          // setup role
    const int slice = (tid >> 2) & 7;    // gather role
    const int g     = tid & 3;           // gather role: channels g*8..g*8+7

    __shared__ float s_valid[8];
    __shared__ float s_red[256][8];      // [tid][chan-in-group]

    if (tid < 6) {
        const int base = (tid * 10000 + q) * 4;
        const int mm = vox[base] | vox[base + 1] | vox[base + 2] | vox[base + 3];
        s_valid[tid] = mm ? 1.0f : 0.0f;
    }

    // ---- softmax over 32 (lvl,p) entries within each head ----
    const float a = bf2f(qkcat[(size_t)q * 768 + 512 + tid]);
    float mx = a;
    #pragma unroll
    for (int o = 16; o >= 1; o >>= 1) mx = fmaxf(mx, __shfl_xor(mx, o));
    const float e = __expf(a - mx);
    float se = e;
    #pragma unroll
    for (int o = 16; o >= 1; o >>= 1) se += __shfl_xor(se, o);
    const float aw = e / se;

    // ---- camera-independent part of this thread's sample location ----
    const int lvl = lp >> 3;
    const int p   = lp & 7;
    const int dd  = p & 3;
    const int   Sarr[4]   = {64, 32, 16, 8};
    const int   Lstart[4] = {0, 4096, 5120, 5376};
    const int   S  = Sarr[lvl];
    const float Sf = (float)S;
    const int   lstart = Lstart[lvl];
    const int   hoff   = h << 6;     // head byte offset within a row (32ch*2B)
    const float ox = bf2f(qkcat[(size_t)q * 768 + h * 64 + lvl * 16 + p * 2 + 0]) / Sf;
    const float oy = bf2f(qkcat[(size_t)q * 768 + h * 64 + lvl * 16 + p * 2 + 1]) / Sf;

    // ---- prefetch ref points for all 6 cams (this lane's dd) ----
    float rx[6], ry[6];
    #pragma unroll
    for (int c = 0; c < 6; ++c) {
        const int rbase = ((c * 10000 + q) * 4 + dd) * 2;
        rx[c] = refp[rbase + 0];
        ry[c] = refp[rbase + 1];
    }

    __syncthreads();
    float sv[6];
    #pragma unroll
    for (int c = 0; c < 6; ++c) sv[c] = s_valid[c];
    const float cnt = sv[0] + sv[1] + sv[2] + sv[3] + sv[4] + sv[5];

    float acc[8] = {0.f, 0.f, 0.f, 0.f, 0.f, 0.f, 0.f, 0.f};
    const char* vpb = (const char*)vproj;
    const int goff = g << 4;             // 4 lanes x 16B within 64B chunk
    const int srcbase = (lane & 32) + slice * 4;

    for (int c = 0; c < 6; ++c) {
        if (sv[c] == 0.0f) continue;     // block-uniform branch

        // ---- setup: corner BYTE offsets + weights for this (h,lvl,p) ----
        int   cb[4];
        float cw[4];
        {
            const int cbase = c * 5440 + lstart;
            const float x  = (rx[c] + ox) * Sf - 0.5f;
            const float y  = (ry[c] + oy) * Sf - 0.5f;
            const float x0 = floorf(x), y0 = floorf(y);
            #pragma unroll
            for (int k = 0; k < 4; ++k) {
                const float cx = x0 + (float)(k & 1);
                const float cy = y0 + (float)(k >> 1);
                const float wgt = (1.0f - fabsf(x - cx)) * (1.0f - fabsf(y - cy));
                const bool ok = (cx >= 0.0f) & (cx < Sf) & (cy >= 0.0f) & (cy < Sf);
                const int xi = (int)fminf(fmaxf(cx, 0.0f), Sf - 1.0f);
                const int yi = (int)fminf(fmaxf(cy, 0.0f), Sf - 1.0f);
                cb[k] = ((cbase + yi * S + xi) << 9) + hoff;   // bytes
                cw[k] = ok ? wgt * aw : 0.0f;
            }
        }

        // ---- exchange byte offsets, issue ALL 16 loads (deep MLP) ----
        int b[4][4];
        #pragma unroll
        for (int j = 0; j < 4; ++j) {
            const int src = srcbase + j;
            b[j][0] = __shfl(cb[0], src);
            b[j][1] = __shfl(cb[1], src);
            b[j][2] = __shfl(cb[2], src);
            b[j][3] = __shfl(cb[3], src);
        }
        uint4 v[4][4];
        #pragma unroll
        for (int j = 0; j < 4; ++j)
            #pragma unroll
            for (int k = 0; k < 4; ++k)
                v[j][k] = *(const uint4*)(vpb + (b[j][k] + goff));

        // ---- exchange weights while loads are in flight ----
        float wf[4][4];
        #pragma unroll
        for (int j = 0; j < 4; ++j) {
            const int src = srcbase + j;
            wf[j][0] = __shfl(cw[0], src);
            wf[j][1] = __shfl(cw[1], src);
            wf[j][2] = __shfl(cw[2], src);
            wf[j][3] = __shfl(cw[3], src);
        }

        // ---- accumulate: 8 channels per lane, f16 halves via fma_mix ----
        #pragma unroll
        for (int j = 0; j < 4; ++j)
            #pragma unroll
            for (int k = 0; k < 4; ++k)
                fma_mix8(acc, wf[j][k], v[j][k]);
    }

    // ---- cross-slice reduction ----
    #pragma unroll
    for (int n = 0; n < 8; ++n) s_red[tid][n] = acc[n];
    __syncthreads();

    const int cch = tid & 31;
    float sum = 0.0f;
    #pragma unroll
    for (int s = 0; s < 8; ++s)
        sum += s_red[h * 32 + s * 4 + (cch >> 3)][cch & 7];

    // slot row overwrites this query's attw logits (all read above)
    qkcat[(size_t)q * 768 + 512 + tid] = f2bf(sum / fmaxf(cnt, 1.0f));
}

// ---------------------------------------------------------------------------
extern "C" void kernel_launch(void* const* d_in, const int* in_sizes, int n_in,
                              void* d_out, int out_size, void* d_ws, size_t ws_size,
                              hipStream_t stream) {
    const float* query   = (const float*)d_in[0];
    // d_in[1] = key : unused by the deformable-attention math
    const float* value   = (const float*)d_in[2];   // (6,5440,1,256) -> (32640,256)
    const float* refp    = (const float*)d_in[3];
    const int*   vox     = (const int*)d_in[4];
    // d_in[5] spatial_shapes, d_in[6] level_start_index : compile-time constants
    const float* value_W = (const float*)d_in[7];
    const float* value_b = (const float*)d_in[8];
    const float* off_W   = (const float*)d_in[9];
    const float* off_b   = (const float*)d_in[10];
    const float* attw_W  = (const float*)d_in[11];
    const float* attw_b  = (const float*)d_in[12];
    const float* out_W   = (const float*)d_in[13];
    const float* out_b   = (const float*)d_in[14];
    float* out = (float*)d_out;

    // ws layout (bytes):
    //   [0,        16711680)  vproj f16 [32640][256]
    //   [16711680, 32071680)  qkcat bf16 [10000][768] (slots in cols 512..768)
    //   [32071680, 32727040)  value_Wt | out_Wt | qk_Wt  bf16
    char* ws = (char*)d_ws;
    ushort_t* vproj    = (ushort_t*)ws;
    ushort_t* qkcat    = (ushort_t*)(ws + 16711680);
    ushort_t* value_Wt = (ushort_t*)(ws + 32071680);
    ushort_t* out_Wt   = (ushort_t*)(ws + 32071680 + 131072);
    ushort_t* qk_Wt    = (ushort_t*)(ws + 32071680 + 262144);

    // 1. weight transpose+convert -> Wt[n][k] bf16
    prep_w<<<dim3(8, 16, 4), 256, 0, stream>>>(
        value_W, out_W, off_W, attw_W, value_Wt, out_Wt, qk_Wt);
    // 2. fused value-proj (f16 out) + offset/attw-proj (bf16 out)
    gemm_vqk<<<984, 256, 0, stream>>>(value, value_Wt, value_b, vproj,
                                      query, qk_Wt, off_b, attw_b, qkcat);
    // 3. deformable sampling + softmax + camera mask/count -> slots in qkcat
    sample_k<<<10000, 256, 0, stream>>>(qkcat, refp, vox, vproj);
    // 4. output projection + residual, f32 out
    gemm_out_k<<<dim3(79, 2), 256, 0, stream>>>(qkcat + 512, out_Wt, out_b,
                                                query, out);
}

// Round 3
// 328.073 us; speedup vs baseline: 1.5479x; 1.1692x over previous
//
#include <hip/hip_runtime.h>

// ---------------------------------------------------------------------------
// SpatialSatCrossAttention (MS deformable attention, 6 cams, 10000 queries)
// R10: sample_k analysis: TA line-touch floor ~94us (57.8M 64B lines); R7's
//     schedule reached 23.5 TB/s (157us) while VALU-bound at 82%; R9's
//     all-16-upfront prefetch was register-capped by the compiler (VGPR=32)
//     and serialized -> 17.8 TB/s. R10 = R7's proven per-j load grouping +
//     f16/v_fma_mix consumption (lower VALU than bf16 unpack) + depth-2
//     pipeline (j+1 loads in flight while consuming j), VGPR budget <= ~64.
// Launches (4):
//   1. prep_w    : weight mats -> Wt[n][k] bf16 (512 blocks)
//   2. gemm_vqk  : vproj = value @ value_W + b  (f16 out)
//                  qkcat = query @ [off|attw]_W (bf16 out)
//   3. sample_k  : deformable bilinear sampling (f16 gather, fma_mix)
//                  -> slots bf16 embedded in qkcat[:,512:768]
//   4. gemm_out  : out = slots @ out_W + out_b + query (f32 d_out)
// GEMM body: 128x128 tile, 4 waves (2x2), 4x4 mfma_f32_16x16x32_bf16, BK=32,
// double-buffered LDS + register prefetch.
// ---------------------------------------------------------------------------

typedef unsigned short ushort_t;
typedef unsigned int uint_t;
typedef __attribute__((ext_vector_type(8))) short bf16x8;
typedef __attribute__((ext_vector_type(4))) float f32x4;

__device__ __forceinline__ float bf2f(ushort_t u) {
    return __uint_as_float(((uint_t)u) << 16);
}
__device__ __forceinline__ ushort_t f2bf(float f) {
    uint_t i = __float_as_uint(f);
    uint_t r = i + 0x7fffu + ((i >> 16) & 1u);   // round-to-nearest-even
    return (ushort_t)(r >> 16);
}
// 8x f32 -> 8x bf16 via v_cvt_pk_bf16_f32 (RNE)
__device__ __forceinline__ bf16x8 pack8(float4 v0, float4 v1) {
    union { uint_t u[4]; bf16x8 v; } r;
    asm("v_cvt_pk_bf16_f32 %0, %1, %2" : "=v"(r.u[0]) : "v"(v0.x), "v"(v0.y));
    asm("v_cvt_pk_bf16_f32 %0, %1, %2" : "=v"(r.u[1]) : "v"(v0.z), "v"(v0.w));
    asm("v_cvt_pk_bf16_f32 %0, %1, %2" : "=v"(r.u[2]) : "v"(v1.x), "v"(v1.y));
    asm("v_cvt_pk_bf16_f32 %0, %1, %2" : "=v"(r.u[3]) : "v"(v1.z), "v"(v1.w));
    return r.v;
}
__device__ __forceinline__ ushort_t f2h(float f) {
    union { _Float16 h; ushort_t u; } cv;
    cv.h = (_Float16)f;
    return cv.u;
}

// acc[0..7] += w * f16x8(v)   -- v_fma_mix_f32, f16 taken from dword halves
__device__ __forceinline__ void fma_mix8(float* a, float wt, const uint4& v) {
    asm("v_fma_mix_f32 %0, %1, %2, %0 op_sel_hi:[0,1,0]"
        : "+v"(a[0]) : "v"(wt), "v"(v.x));
    asm("v_fma_mix_f32 %0, %1, %2, %0 op_sel:[0,1,0] op_sel_hi:[0,1,0]"
        : "+v"(a[1]) : "v"(wt), "v"(v.x));
    asm("v_fma_mix_f32 %0, %1, %2, %0 op_sel_hi:[0,1,0]"
        : "+v"(a[2]) : "v"(wt), "v"(v.y));
    asm("v_fma_mix_f32 %0, %1, %2, %0 op_sel:[0,1,0] op_sel_hi:[0,1,0]"
        : "+v"(a[3]) : "v"(wt), "v"(v.y));
    asm("v_fma_mix_f32 %0, %1, %2, %0 op_sel_hi:[0,1,0]"
        : "+v"(a[4]) : "v"(wt), "v"(v.z));
    asm("v_fma_mix_f32 %0, %1, %2, %0 op_sel:[0,1,0] op_sel_hi:[0,1,0]"
        : "+v"(a[5]) : "v"(wt), "v"(v.z));
    asm("v_fma_mix_f32 %0, %1, %2, %0 op_sel_hi:[0,1,0]"
        : "+v"(a[6]) : "v"(wt), "v"(v.w));
    asm("v_fma_mix_f32 %0, %1, %2, %0 op_sel:[0,1,0] op_sel_hi:[0,1,0]"
        : "+v"(a[7]) : "v"(wt), "v"(v.w));
}

// ---------------------------------------------------------------------------
// prep_w: weight transpose+convert only. W[k][N] f32 -> T[n][256] bf16.
// grid (8,16,4): z=0 value_W, z=1 out_W, z=2 off_W(512), z=3 attw_W.
// ---------------------------------------------------------------------------
__global__ __launch_bounds__(256) void prep_w(
    const float* __restrict__ Wv, const float* __restrict__ Wo,
    const float* __restrict__ Wf, const float* __restrict__ Wa,
    ushort_t* __restrict__ Tv, ushort_t* __restrict__ To,
    ushort_t* __restrict__ Tqk) {
    const int z = blockIdx.z;
    const float* W;
    ushort_t* T;
    int N;
    if (z == 0)      { W = Wv; T = Tv;              N = 256; }
    else if (z == 1) { W = Wo; T = To;              N = 256; }
    else if (z == 2) { W = Wf; T = Tqk;             N = 512; }
    else             { W = Wa; T = Tqk + 512 * 256; N = 256; }
    const int n0 = blockIdx.y * 32;
    if (n0 >= N) return;
    const int k0 = blockIdx.x * 32;

    __shared__ float tile[32][33];
    const int tx = threadIdx.x & 31;
    const int ty = threadIdx.x >> 5;   // 0..7
    #pragma unroll
    for (int r = 0; r < 4; ++r) {
        const int k = ty + r * 8;
        tile[k][tx] = W[(size_t)(k0 + k) * N + n0 + tx];
    }
    __syncthreads();
    #pragma unroll
    for (int r = 0; r < 4; ++r) {
        const int n = ty + r * 8;
        T[(size_t)(n0 + n) * 256 + k0 + tx] = f2bf(tile[tx][n]);
    }
}

// ---------------------------------------------------------------------------
// MFMA GEMM body: C[M,N] = A[M,256] @ Wt^T + bias (+resid).
// AF32: A is f32, converted to bf16 during LDS staging; else A is bf16.
// OUT_MODE: 0 = f32, 1 = bf16, 2 = f16.
// Astride: element stride between A rows (slots live embedded in qkcat).
// Wt bf16 [N][256]. N multiple of 128. 256 threads, 128x128 tile.
// ---------------------------------------------------------------------------
template <bool AF32, int OUT_MODE, bool RESID>
__device__ __forceinline__ void gemm_body(
    ushort_t (*sA)[128][32], ushort_t (*sB)[128][32],
    const void* __restrict__ Av, int Astride, const ushort_t* __restrict__ Wt,
    const float* __restrict__ bias0, const float* __restrict__ bias1, int split,
    const float* __restrict__ resid, void* __restrict__ Cv,
    int M, int N, int bx, int by) {
    const int m0 = bx * 128;
    const int n0 = by * 128;
    const int t    = threadIdx.x;
    const int lane = t & 63;
    const int w    = t >> 6;
    const int wr   = w >> 1, wc = w & 1;

    const int srow = t >> 2;          // 0..63
    const int skof = (t & 3) * 8;     // 0,8,16,24

    const bool am0 = (m0 + srow) < M;
    const bool am1 = (m0 + 64 + srow) < M;
    const float*    Af0 = (const float*)Av + (size_t)(m0 + srow) * Astride + skof;
    const float*    Af1 = Af0 + (size_t)64 * Astride;
    const ushort_t* Ab0 = (const ushort_t*)Av + (size_t)(m0 + srow) * Astride + skof;
    const ushort_t* Ab1 = Ab0 + (size_t)64 * Astride;
    const ushort_t* Bp0 = Wt + (size_t)(n0 + srow) * 256 + skof;
    const ushort_t* Bp1 = Bp0 + (size_t)64 * 256;

    const bf16x8 zz = {0, 0, 0, 0, 0, 0, 0, 0};

    auto loadA = [&](const float* af, const ushort_t* ab, int ko, bool ok) -> bf16x8 {
        if (!ok) return zz;
        if (AF32) {
            const float4 v0 = *(const float4*)(af + ko);
            const float4 v1 = *(const float4*)(af + ko + 4);
            return pack8(v0, v1);
        }
        return *(const bf16x8*)(ab + ko);
    };

    f32x4 acc[4][4];
    #pragma unroll
    for (int i = 0; i < 4; ++i)
        #pragma unroll
        for (int j = 0; j < 4; ++j)
            acc[i][j] = (f32x4){0.f, 0.f, 0.f, 0.f};

    // prologue: tile 0 -> LDS[0]
    {
        const bf16x8 a0 = loadA(Af0, Ab0, 0, am0);
        const bf16x8 a1 = loadA(Af1, Ab1, 0, am1);
        const bf16x8 b0 = *(const bf16x8*)(Bp0);
        const bf16x8 b1 = *(const bf16x8*)(Bp1);
        *(bf16x8*)(&sA[0][srow][skof])      = a0;
        *(bf16x8*)(&sA[0][64 + srow][skof]) = a1;
        *(bf16x8*)(&sB[0][srow][skof])      = b0;
        *(bf16x8*)(&sB[0][64 + srow][skof]) = b1;
    }
    __syncthreads();

    const int rl = lane & 15;
    const int kq = (lane >> 4) * 8;

    for (int k = 0; k < 8; ++k) {
        const int buf = k & 1;

        bf16x8 na0 = zz, na1 = zz, nb0 = zz, nb1 = zz;
        if (k < 7) {
            const int ko = (k + 1) * 32;
            na0 = loadA(Af0, Ab0, ko, am0);
            na1 = loadA(Af1, Ab1, ko, am1);
            nb0 = *(const bf16x8*)(Bp0 + ko);
            nb1 = *(const bf16x8*)(Bp1 + ko);
        }

        bf16x8 af[4], bfr[4];
        #pragma unroll
        for (int i = 0; i < 4; ++i)
            af[i] = *(const bf16x8*)(&sA[buf][wr * 64 + i * 16 + rl][kq]);
        #pragma unroll
        for (int j = 0; j < 4; ++j)
            bfr[j] = *(const bf16x8*)(&sB[buf][wc * 64 + j * 16 + rl][kq]);
        #pragma unroll
        for (int i = 0; i < 4; ++i)
            #pragma unroll
            for (int j = 0; j < 4; ++j)
                acc[i][j] = __builtin_amdgcn_mfma_f32_16x16x32_bf16(
                    af[i], bfr[j], acc[i][j], 0, 0, 0);

        if (k < 7) {
            __syncthreads();
            *(bf16x8*)(&sA[buf ^ 1][srow][skof])      = na0;
            *(bf16x8*)(&sA[buf ^ 1][64 + srow][skof]) = na1;
            *(bf16x8*)(&sB[buf ^ 1][srow][skof])      = nb0;
            *(bf16x8*)(&sB[buf ^ 1][64 + srow][skof]) = nb1;
            __syncthreads();
        }
    }

    // --- epilogue: C/D layout col=lane&15, row=(lane>>4)*4+reg (m89) ---
    const int col_l = lane & 15;
    const int rq    = (lane >> 4) * 4;
    #pragma unroll
    for (int j = 0; j < 4; ++j) {
        const int gn = n0 + wc * 64 + j * 16 + col_l;
        const float bj = (gn < split) ? bias0[gn] : bias1[gn - split];
        #pragma unroll
        for (int i = 0; i < 4; ++i) {
            #pragma unroll
            for (int r = 0; r < 4; ++r) {
                const int gm = m0 + wr * 64 + i * 16 + rq + r;
                if (gm >= M) continue;
                float v = acc[i][j][r] + bj;
                if (RESID) v += resid[(size_t)gm * N + gn];
                if (OUT_MODE == 1)
                    ((ushort_t*)Cv)[(size_t)gm * N + gn] = f2bf(v);
                else if (OUT_MODE == 2)
                    ((ushort_t*)Cv)[(size_t)gm * N + gn] = f2h(v);
                else
                    ((float*)Cv)[(size_t)gm * N + gn] = v;
            }
        }
    }
}

// Fused independent GEMMs: blocks [0,510) -> vproj (f16 out),
//                          [510,984) -> qkcat (bf16 out).
__global__ __launch_bounds__(256) void gemm_vqk(
    const float* __restrict__ value, const ushort_t* __restrict__ value_Wt,
    const float* __restrict__ value_b, ushort_t* __restrict__ vproj,
    const float* __restrict__ query, const ushort_t* __restrict__ qk_Wt,
    const float* __restrict__ off_b, const float* __restrict__ attw_b,
    ushort_t* __restrict__ qkcat) {
    __shared__ ushort_t sA[2][128][32];
    __shared__ ushort_t sB[2][128][32];
    int b = blockIdx.x;
    if (b < 510) {
        gemm_body<true, 2, false>(sA, sB, value, 256, value_Wt, value_b,
                                  value_b, 256, nullptr, (void*)vproj,
                                  32640, 256, b % 255, b / 255);
    } else {
        b -= 510;
        gemm_body<true, 1, false>(sA, sB, query, 256, qk_Wt, off_b, attw_b,
                                  512, nullptr, (void*)qkcat, 10000, 768,
                                  b % 79, b / 79);
    }
}

__global__ __launch_bounds__(256) void gemm_out_k(
    const ushort_t* __restrict__ slots,   // = qkcat + 512, row stride 768
    const ushort_t* __restrict__ out_Wt,
    const float* __restrict__ out_b, const float* __restrict__ query,
    float* __restrict__ out) {
    __shared__ ushort_t sA[2][128][32];
    __shared__ ushort_t sB[2][128][32];
    gemm_body<false, 0, true>(sA, sB, slots, 768, out_Wt, out_b, out_b, 256,
                              query, (void*)out, 10000, 256,
                              blockIdx.x, blockIdx.y);
}

// ---------------------------------------------------------------------------
// Deformable sampling. 1 block per query, 256 threads.
//   setup role : (h, lp = tid&31)  -> corner byte-offset/weight for (h,lvl,p)
//   gather role: (h, slice, g)     -> 16B f16 loads, v_fma_mix accumulate
// R7-proven per-j load grouping with depth-2 pipeline: group j+1's 4 loads
// issued before group j is consumed. Corner (idx,w) exchanged via __shfl.
// Slot row written back into qkcat[:,512:768) as bf16.
// ---------------------------------------------------------------------------
__global__ __launch_bounds__(256) void sample_k(
    ushort_t* __restrict__ qkcat,        // bf16 [10000, 768]
    const float* __restrict__ refp,      // f32 [6,1,10000,4,2]
    const int* __restrict__ vox,         // int32 [6,1,10000,4]
    const ushort_t* __restrict__ vproj) {// f16 [6*5440, 256]
    const int q   = blockIdx.x;
    const int tid = threadIdx.x;
    const int lane  = tid & 63;
    const int h     = tid >> 5;
    const int lp    = tid & 31;          // setup role
    const int slice = (tid >> 2) & 7;    // gather role
    const int g     = tid & 3;           // gather role: channels g*8..g*8+7

    __shared__ float s_valid[8];
    __shared__ float s_red[256][8];      // [tid][chan-in-group]

    if (tid < 6) {
        const int base = (tid * 10000 + q) * 4;
        const int mm = vox[base] | vox[base + 1] | vox[base + 2] | vox[base + 3];
        s_valid[tid] = mm ? 1.0f : 0.0f;
    }

    // ---- softmax over 32 (lvl,p) entries within each head ----
    const float a = bf2f(qkcat[(size_t)q * 768 + 512 + tid]);
    float mx = a;
    #pragma unroll
    for (int o = 16; o >= 1; o >>= 1) mx = fmaxf(mx, __shfl_xor(mx, o));
    const float e = __expf(a - mx);
    float se = e;
    #pragma unroll
    for (int o = 16; o >= 1; o >>= 1) se += __shfl_xor(se, o);
    const float aw = e / se;

    // ---- camera-independent part of this thread's sample location ----
    const int lvl = lp >> 3;
    const int p   = lp & 7;
    const int dd  = p & 3;
    const int   Sarr[4]   = {64, 32, 16, 8};
    const int   Lstart[4] = {0, 4096, 5120, 5376};
    const int   S  = Sarr[lvl];
    const float Sf = (float)S;
    const int   lstart = Lstart[lvl];
    const int   hoff   = h << 6;     // head byte offset within a row (32ch*2B)
    const float ox = bf2f(qkcat[(size_t)q * 768 + h * 64 + lvl * 16 + p * 2 + 0]) / Sf;
    const float oy = bf2f(qkcat[(size_t)q * 768 + h * 64 + lvl * 16 + p * 2 + 1]) / Sf;

    __syncthreads();
    float sv[6];
    #pragma unroll
    for (int c = 0; c < 6; ++c) sv[c] = s_valid[c];
    const float cnt = sv[0] + sv[1] + sv[2] + sv[3] + sv[4] + sv[5];

    float acc[8] = {0.f, 0.f, 0.f, 0.f, 0.f, 0.f, 0.f, 0.f};
    const char* vpb = (const char*)vproj;
    const int goff = g << 4;             // 4 lanes x 16B within 64B chunk
    const int srcbase = (lane & 32) + slice * 4;

    for (int c = 0; c < 6; ++c) {
        if (sv[c] == 0.0f) continue;     // block-uniform branch

        // ---- setup: corner BYTE offsets + weights for this (h,lvl,p) ----
        int   cb[4];
        float cw[4];
        {
            const int cbase = c * 5440 + lstart;
            const int rbase = ((c * 10000 + q) * 4 + dd) * 2;
            const float rx = refp[rbase + 0];
            const float ry = refp[rbase + 1];
            const float x  = (rx + ox) * Sf - 0.5f;
            const float y  = (ry + oy) * Sf - 0.5f;
            const float x0 = floorf(x), y0 = floorf(y);
            #pragma unroll
            for (int k = 0; k < 4; ++k) {
                const float cx = x0 + (float)(k & 1);
                const float cy = y0 + (float)(k >> 1);
                const float wgt = (1.0f - fabsf(x - cx)) * (1.0f - fabsf(y - cy));
                const bool ok = (cx >= 0.0f) & (cx < Sf) & (cy >= 0.0f) & (cy < Sf);
                const int xi = (int)fminf(fmaxf(cx, 0.0f), Sf - 1.0f);
                const int yi = (int)fminf(fmaxf(cy, 0.0f), Sf - 1.0f);
                cb[k] = ((cbase + yi * S + xi) << 9) + hoff;   // bytes
                cw[k] = ok ? wgt * aw : 0.0f;
            }
        }

        // ---- exchange byte offsets for all 4 groups ----
        int b[4][4];
        #pragma unroll
        for (int j = 0; j < 4; ++j) {
            const int src = srcbase + j;
            b[j][0] = __shfl(cb[0], src);
            b[j][1] = __shfl(cb[1], src);
            b[j][2] = __shfl(cb[2], src);
            b[j][3] = __shfl(cb[3], src);
        }

        // ---- depth-2 pipelined gather: group j+1 in flight during j ----
        uint4 v0 = *(const uint4*)(vpb + (b[0][0] + goff));
        uint4 v1 = *(const uint4*)(vpb + (b[0][1] + goff));
        uint4 v2 = *(const uint4*)(vpb + (b[0][2] + goff));
        uint4 v3 = *(const uint4*)(vpb + (b[0][3] + goff));
        #pragma unroll
        for (int j = 0; j < 4; ++j) {
            uint4 n0 = v0, n1 = v1, n2 = v2, n3 = v3;
            if (j < 3) {
                n0 = *(const uint4*)(vpb + (b[j + 1][0] + goff));
                n1 = *(const uint4*)(vpb + (b[j + 1][1] + goff));
                n2 = *(const uint4*)(vpb + (b[j + 1][2] + goff));
                n3 = *(const uint4*)(vpb + (b[j + 1][3] + goff));
            }
            const int src = srcbase + j;
            const float w0 = __shfl(cw[0], src), w1 = __shfl(cw[1], src);
            const float w2 = __shfl(cw[2], src), w3 = __shfl(cw[3], src);
            fma_mix8(acc, w0, v0);
            fma_mix8(acc, w1, v1);
            fma_mix8(acc, w2, v2);
            fma_mix8(acc, w3, v3);
            v0 = n0; v1 = n1; v2 = n2; v3 = n3;
        }
    }

    // ---- cross-slice reduction ----
    #pragma unroll
    for (int n = 0; n < 8; ++n) s_red[tid][n] = acc[n];
    __syncthreads();

    const int cch = tid & 31;
    float sum = 0.0f;
    #pragma unroll
    for (int s = 0; s < 8; ++s)
        sum += s_red[h * 32 + s * 4 + (cch >> 3)][cch & 7];

    // slot row overwrites this query's attw logits (all read above)
    qkcat[(size_t)q * 768 + 512 + tid] = f2bf(sum / fmaxf(cnt, 1.0f));
}

// ---------------------------------------------------------------------------
extern "C" void kernel_launch(void* const* d_in, const int* in_sizes, int n_in,
                              void* d_out, int out_size, void* d_ws, size_t ws_size,
                              hipStream_t stream) {
    const float* query   = (const float*)d_in[0];
    // d_in[1] = key : unused by the deformable-attention math
    const float* value   = (const float*)d_in[2];   // (6,5440,1,256) -> (32640,256)
    const float* refp    = (const float*)d_in[3];
    const int*   vox     = (const int*)d_in[4];
    // d_in[5] spatial_shapes, d_in[6] level_start_index : compile-time constants
    const float* value_W = (const float*)d_in[7];
    const float* value_b = (const float*)d_in[8];
    const float* off_W   = (const float*)d_in[9];
    const float* off_b   = (const float*)d_in[10];
    const float* attw_W  = (const float*)d_in[11];
    const float* attw_b  = (const float*)d_in[12];
    const float* out_W   = (const float*)d_in[13];
    const float* out_b   = (const float*)d_in[14];
    float* out = (float*)d_out;

    // ws layout (bytes):
    //   [0,        16711680)  vproj f16 [32640][256]
    //   [16711680, 32071680)  qkcat bf16 [10000][768] (slots in cols 512..768)
    //   [32071680, 32727040)  value_Wt | out_Wt | qk_Wt  bf16
    char* ws = (char*)d_ws;
    ushort_t* vproj    = (ushort_t*)ws;
    ushort_t* qkcat    = (ushort_t*)(ws + 16711680);
    ushort_t* value_Wt = (ushort_t*)(ws + 32071680);
    ushort_t* out_Wt   = (ushort_t*)(ws + 32071680 + 131072);
    ushort_t* qk_Wt    = (ushort_t*)(ws + 32071680 + 262144);

    // 1. weight transpose+convert -> Wt[n][k] bf16
    prep_w<<<dim3(8, 16, 4), 256, 0, stream>>>(
        value_W, out_W, off_W, attw_W, value_Wt, out_Wt, qk_Wt);
    // 2. fused value-proj (f16 out) + offset/attw-proj (bf16 out)
    gemm_vqk<<<984, 256, 0, stream>>>(value, value_Wt, value_b, vproj,
                                      query, qk_Wt, off_b, attw_b, qkcat);
    // 3. deformable sampling + softmax + camera mask/count -> slots in qkcat
    sample_k<<<10000, 256, 0, stream>>>(qkcat, refp, vox, vproj);
    // 4. output projection + residual, f32 out
    gemm_out_k<<<dim3(79, 2), 256, 0, stream>>>(qkcat + 512, out_Wt, out_b,
                                                query, out);
}